// Round 11
// baseline (258.101 us; speedup 1.0000x reference)
//
#include <hip/hip_runtime.h>
#include <hip/hip_bf16.h>
#include <stdint.h>
#include <stddef.h>

#define N_ 4096
#define D_ 64
#define I_ 512
#define O_ 512

#define BM 256
#define BN 256
#define SPLITS 8
#define DPG 8                  /* d-values per block */
#define NT 64                  /* K-tiles of 64: DPG * (I_/64) */

typedef float  floatx4 __attribute__((ext_vector_type(4)));
typedef short  shortx8 __attribute__((ext_vector_type(8)));
typedef __bf16 bf16x8  __attribute__((ext_vector_type(8)));

__device__ __forceinline__ void gload_lds16(const void* g, void* l) {
  __builtin_amdgcn_global_load_lds(
      (const __attribute__((address_space(1))) void*)g,
      (__attribute__((address_space(3))) void*)l, 16, 0, 0);
}

__device__ __forceinline__ unsigned short f2bf(float f) {
  union { float f; unsigned int u; } c; c.f = f;
  unsigned int u = c.u;
  return (unsigned short)((u + 0x7fffu + ((u >> 16) & 1u)) >> 16);  // RNE
}

__device__ __forceinline__ void mfma_bf16(floatx4& c, shortx8 a, shortx8 b) {
  union { shortx8 s; bf16x8 h; } ua, ub;
  ua.s = a; ub.s = b;
  c = __builtin_amdgcn_mfma_f32_16x16x32_bf16(ua.h, ub.h, c, 0, 0, 0);
}

// av' = bf16(v * f32(av)) — var folded into the A operand (one scalar/lane:
// the 16x16x32 A-frag is row-per-lane). ~20 VALU; cvt_pk is RNE.
__device__ __forceinline__ shortx8 scale_frag(shortx8 a, float v) {
  union { shortx8 s; unsigned int u[4]; } x, r;
  x.s = a;
  #pragma unroll
  for (int i = 0; i < 4; ++i) {
    float lo = __uint_as_float(x.u[i] << 16) * v;
    float hi = __uint_as_float(x.u[i] & 0xffff0000u) * v;
    unsigned int ro;
    asm("v_cvt_pk_bf16_f32 %0, %1, %2" : "=v"(ro) : "v"(lo), "v"(hi));
    r.u[i] = ro;
  }
  return r.s;
}

// ---------- pre-pass: x fp32 -> bf16 ----------
__global__ void k_cvt_x(const float* __restrict__ x, unsigned short* __restrict__ xb) {
  int idx = (blockIdx.x * blockDim.x + threadIdx.x) * 8;
  floatx4 a = *(const floatx4*)(x + idx);
  floatx4 b = *(const floatx4*)(x + idx + 4);
  shortx8 o;
  o[0] = (short)f2bf(a[0]); o[1] = (short)f2bf(a[1]);
  o[2] = (short)f2bf(a[2]); o[3] = (short)f2bf(a[3]);
  o[4] = (short)f2bf(b[0]); o[5] = (short)f2bf(b[1]);
  o[6] = (short)f2bf(b[2]); o[7] = (short)f2bf(b[3]);
  *(shortx8*)(xb + idx) = o;
}

// ---------- pre-pass: W[d][i][o] fp32 -> Wt[d][o][i] bf16 (transpose) ----------
__global__ void k_cvt_w(const float* __restrict__ w, unsigned short* __restrict__ wt) {
  __shared__ unsigned short T[64][72];
  int bid = blockIdx.x;
  int d  = bid >> 6;
  int it = (bid >> 3) & 7;
  int ot = bid & 7;
  int i0 = it * 64, o0 = ot * 64;
  int t = threadIdx.x;
  const float* wp = w + ((size_t)d * I_ + i0) * O_ + o0;
  #pragma unroll
  for (int j = 0; j < 16; ++j) {
    int idx = j * 256 + t;
    int r = idx >> 6, c = idx & 63;
    T[r][c] = f2bf(wp[(size_t)r * O_ + c]);
  }
  __syncthreads();
  unsigned short* op = wt + ((size_t)d * O_ + o0) * I_ + i0;
  #pragma unroll
  for (int j = 0; j < 16; ++j) {
    int idx = j * 256 + t;
    int r = idx >> 6, c = idx & 63;
    op[(size_t)r * I_ + c] = T[c][r];
  }
}

// ---------- bias: out[n,o] = sum_d var[n,d] * b1[d,o]  (zero-init + bias) ----------
__global__ void k_bias(const float* __restrict__ var, const float* __restrict__ b1,
                       float* __restrict__ out) {
  __shared__ float vs[16][64];
  int n0 = blockIdx.x * 16;
  int t = threadIdx.x;
  #pragma unroll
  for (int j = 0; j < 4; ++j) {
    int idx = j * 256 + t;
    vs[idx >> 6][idx & 63] = var[(size_t)n0 * D_ + idx];
  }
  __syncthreads();
  float a0[16], a1[16];
  #pragma unroll
  for (int r = 0; r < 16; ++r) { a0[r] = 0.f; a1[r] = 0.f; }
  for (int d = 0; d < D_; ++d) {
    float b0 = b1[(size_t)d * O_ + t];
    float bb = b1[(size_t)d * O_ + 256 + t];
    #pragma unroll
    for (int r = 0; r < 16; ++r) { a0[r] += vs[r][d] * b0; a1[r] += vs[r][d] * bb; }
  }
  #pragma unroll
  for (int r = 0; r < 16; ++r) {
    out[(size_t)(n0 + r) * O_ + t]       = a0[r];
    out[(size_t)(n0 + r) * O_ + 256 + t] = a1[r];
  }
}

// ---------- main: m201-style 256x256, 4-phase/K-tile, counted vmcnt(4), var-in-A ----------
// Per K-tile t (d = t>>3, kk = t&7): phases {ph0: av m0-3 kh0 + bv kh0 (8 rd),
// stage A-kh0(t+1); ph1: av m4-7 kh0 (4 rd), stage B-kh0(t+1), vmcnt(4)=kh1(t);
// ph2/ph3: same on kh1, ph3 vmcnt(4)=kh0(t+1)}. Each phase: reads -> stage ->
// scale(lgkm by compiler) -> bar -> setprio 16 MFMA -> [vmcnt] -> bar.
// Queue invariant at ph0 entry: 4 outstanding (kh1(t)); peaks at 8; vmcnt
// never drains to 0 mid-loop (T4). LDS dbuf=2, halves split by k (publication
// aligns with phase consumption). Single acc[8][4] — var folded into A.
__global__ __launch_bounds__(512) void k_gemm(
    const unsigned short* __restrict__ xb, const unsigned short* __restrict__ wt,
    const float* __restrict__ var, float* __restrict__ out) {
  __shared__ alignas(16) char lA[2][2][16384];   // [buf][kh] 64 KB
  __shared__ alignas(16) char lB[2][2][16384];   // 64 KB
  __shared__ alignas(16) float lV[DPG * BM];     // 8 KB

  const int tid = threadIdx.x;
  const int bid = blockIdx.x;
  const int g  = bid & 15;          // (ot,split): all 16 mt-blocks of one
  const int mt = bid >> 4;          // W-slice land on XCD g&7 (bid%8 == g%8)
  const int ot = g >> 3, split = g & 7;
  const int brow = mt * BM, bcol = ot * BN, d0 = split * DPG;

  const int lane = tid & 63, wid = tid >> 6;
  const int wr = wid >> 2, wc = wid & 3;        // 2M x 4N waves, 128x64 each
  const int l15 = lane & 15, l4 = lane >> 4;

  // lV[dd*256 + row] = var[brow+row][d0+dd]
  #pragma unroll
  for (int j = 0; j < (DPG * BM) / 512; ++j) {
    int idx = j * 512 + tid;
    lV[idx] = var[(size_t)(brow + (idx & 255)) * D_ + d0 + (idx >> 8)];
  }

  const char* xbB = (const char*)xb;
  const char* wtB = (const char*)wt;
  const size_t IO2 = (size_t)I_ * O_ * 2;

  // staging constants: linear LDS dest (gload contract), inverse-swizzled
  // global source. Half = 256 rows x 32 k = 16 KB packed [128][128B].
  int pb[2]; size_t gA[2], gB[2];
  #pragma unroll
  for (int c = 0; c < 2; ++c) {
    int p = (c * 512 + tid) << 4;
    int rl = p >> 7;
    int colG = (p & 127) ^ ((rl & 7) << 4);
    int rs = rl + ((colG >> 6) << 7);        // [0,256)
    int ks = (colG & 63) >> 1;               // [0,32)
    pb[c] = p;
    gA[c] = ((size_t)(brow + rs) * I_ + ks) * 2;
    gB[c] = ((size_t)(bcol + rs) * I_ + ks) * 2;
  }

  // read offsets (tid-constant)
  int avOff[8], bvOff[4];
  #pragma unroll
  for (int m = 0; m < 8; ++m) {
    int r = wr * 128 + m * 16 + l15;
    int rl = r & 127;
    avOff[m] = rl * 128 + ((((r >> 7) << 6) + l4 * 16) ^ ((rl & 7) << 4));
  }
  #pragma unroll
  for (int n = 0; n < 4; ++n) {
    int c = wc * 64 + n * 16 + l15;
    int rl = c & 127;
    bvOff[n] = rl * 128 + ((((c >> 7) << 6) + l4 * 16) ^ ((rl & 7) << 4));
  }

  auto stgA = [&](int t, int kh) {
    char* dst = &lA[t & 1][kh][0];
    size_t ko = (size_t)((t & 7) * 128 + kh * 64);
    gload_lds16(xbB + gA[0] + ko, dst + pb[0]);
    gload_lds16(xbB + gA[1] + ko, dst + pb[1]);
  };
  auto stgB = [&](int t, int kh) {
    char* dst = &lB[t & 1][kh][0];
    const char* src = wtB + (size_t)(d0 + (t >> 3)) * IO2
                          + (size_t)((t & 7) * 128 + kh * 64);
    gload_lds16(src + gB[0], dst + pb[0]);
    gload_lds16(src + gB[1], dst + pb[1]);
  };

  const floatx4 vzero = {0.f, 0.f, 0.f, 0.f};
  floatx4 acc[8][4];
  #pragma unroll
  for (int m = 0; m < 8; ++m)
    #pragma unroll
    for (int n = 0; n < 4; ++n) acc[m][n] = vzero;
  float vv[8];

  // prologue: kh0(0) 4 loads + kh1(0) 4; certify kh0 (vmcnt(4) leaves kh1
  // flying = steady-state invariant); drain lgkm (lV writes); barrier.
  stgA(0, 0); stgB(0, 0); stgA(0, 1); stgB(0, 1);
  asm volatile("s_waitcnt vmcnt(4) lgkmcnt(0)" ::: "memory");
  __builtin_amdgcn_sched_barrier(0);
  __builtin_amdgcn_s_barrier();
  __builtin_amdgcn_sched_barrier(0);

  #pragma unroll 1
  for (int t = 0; t < NT; ++t) {
    const int buf = t & 1;
    const char* a0 = &lA[buf][0][0];
    const char* a1 = &lA[buf][1][0];
    const char* b0 = &lB[buf][0][0];
    const char* b1 = &lB[buf][1][0];
    const bool pre = (t + 1 < NT);
    shortx8 av[4], bv[4];

    if ((t & 7) == 0) {                       // d-boundary: refresh var regs
      #pragma unroll
      for (int m = 0; m < 8; ++m)
        vv[m] = lV[((t >> 3) << 8) + wr * 128 + m * 16 + l15];
    }

    // ---- ph0: av m0-3 kh0 + bv kh0 | stage A-kh0(t+1) | MFMA acc[0-3] ----
    #pragma unroll
    for (int m = 0; m < 4; ++m) av[m] = *(const shortx8*)(a0 + avOff[m]);
    #pragma unroll
    for (int n = 0; n < 4; ++n) bv[n] = *(const shortx8*)(b0 + bvOff[n]);
    if (pre) stgA(t + 1, 0);
    #pragma unroll
    for (int m = 0; m < 4; ++m) av[m] = scale_frag(av[m], vv[m]);
    __builtin_amdgcn_sched_barrier(0);
    __builtin_amdgcn_s_barrier();
    __builtin_amdgcn_sched_barrier(0);
    __builtin_amdgcn_s_setprio(1);
    #pragma unroll
    for (int m = 0; m < 4; ++m)
      #pragma unroll
      for (int n = 0; n < 4; ++n) mfma_bf16(acc[m][n], av[m], bv[n]);
    __builtin_amdgcn_s_setprio(0);
    __builtin_amdgcn_sched_barrier(0);
    __builtin_amdgcn_s_barrier();
    __builtin_amdgcn_sched_barrier(0);

    // ---- ph1: av m4-7 kh0 | stage B-kh0(t+1) | MFMA acc[4-7] | vmcnt=kh1(t) ----
    #pragma unroll
    for (int m = 0; m < 4; ++m) av[m] = *(const shortx8*)(a0 + avOff[4 + m]);
    if (pre) stgB(t + 1, 0);
    #pragma unroll
    for (int m = 0; m < 4; ++m) av[m] = scale_frag(av[m], vv[4 + m]);
    __builtin_amdgcn_sched_barrier(0);
    __builtin_amdgcn_s_barrier();
    __builtin_amdgcn_sched_barrier(0);
    __builtin_amdgcn_s_setprio(1);
    #pragma unroll
    for (int m = 0; m < 4; ++m)
      #pragma unroll
      for (int n = 0; n < 4; ++n) mfma_bf16(acc[4 + m][n], av[m], bv[n]);
    __builtin_amdgcn_s_setprio(0);
    if (pre) { asm volatile("s_waitcnt vmcnt(4)" ::: "memory"); }
    else     { asm volatile("s_waitcnt vmcnt(0)" ::: "memory"); }
    __builtin_amdgcn_sched_barrier(0);
    __builtin_amdgcn_s_barrier();
    __builtin_amdgcn_sched_barrier(0);

    // ---- ph2: av m0-3 kh1 + bv kh1 | stage A-kh1(t+1) | MFMA acc[0-3] ----
    #pragma unroll
    for (int m = 0; m < 4; ++m) av[m] = *(const shortx8*)(a1 + avOff[m]);
    #pragma unroll
    for (int n = 0; n < 4; ++n) bv[n] = *(const shortx8*)(b1 + bvOff[n]);
    if (pre) stgA(t + 1, 1);
    #pragma unroll
    for (int m = 0; m < 4; ++m) av[m] = scale_frag(av[m], vv[m]);
    __builtin_amdgcn_sched_barrier(0);
    __builtin_amdgcn_s_barrier();
    __builtin_amdgcn_sched_barrier(0);
    __builtin_amdgcn_s_setprio(1);
    #pragma unroll
    for (int m = 0; m < 4; ++m)
      #pragma unroll
      for (int n = 0; n < 4; ++n) mfma_bf16(acc[m][n], av[m], bv[n]);
    __builtin_amdgcn_s_setprio(0);
    __builtin_amdgcn_sched_barrier(0);
    __builtin_amdgcn_s_barrier();
    __builtin_amdgcn_sched_barrier(0);

    // ---- ph3: av m4-7 kh1 | stage B-kh1(t+1) | MFMA acc[4-7] | vmcnt=kh0(t+1) ----
    #pragma unroll
    for (int m = 0; m < 4; ++m) av[m] = *(const shortx8*)(a1 + avOff[4 + m]);
    if (pre) stgB(t + 1, 1);
    #pragma unroll
    for (int m = 0; m < 4; ++m) av[m] = scale_frag(av[m], vv[4 + m]);
    __builtin_amdgcn_sched_barrier(0);
    __builtin_amdgcn_s_barrier();
    __builtin_amdgcn_sched_barrier(0);
    __builtin_amdgcn_s_setprio(1);
    #pragma unroll
    for (int m = 0; m < 4; ++m)
      #pragma unroll
      for (int n = 0; n < 4; ++n) mfma_bf16(acc[4 + m][n], av[m], bv[n]);
    __builtin_amdgcn_s_setprio(0);
    if (pre) { asm volatile("s_waitcnt vmcnt(4)" ::: "memory"); }
    __builtin_amdgcn_sched_barrier(0);
    __builtin_amdgcn_s_barrier();
    __builtin_amdgcn_sched_barrier(0);
  }

  // epilogue: var already folded — plain atomic accumulate across splits
  #pragma unroll
  for (int m = 0; m < 8; ++m) {
    int row0 = brow + wr * 128 + m * 16 + l4 * 4;
    #pragma unroll
    for (int n = 0; n < 4; ++n) {
      int col = bcol + wc * 64 + n * 16 + l15;
      #pragma unroll
      for (int r = 0; r < 4; ++r)
        atomicAdd(out + (size_t)(row0 + r) * O_ + col, acc[m][n][r]);
    }
  }
}

// ---------- fallback (only if ws too small for bf16 staging) ----------
__global__ void k_naive(const float* __restrict__ x, const float* __restrict__ var,
                        const float* __restrict__ w, const float* __restrict__ b1,
                        float* __restrict__ out) {
  int n = blockIdx.x;
  int o = blockIdx.y * 128 + threadIdx.x;
  const float* xp = x + (size_t)n * I_;
  float acc = 0.f;
  for (int d = 0; d < D_; ++d) {
    const float* wp = w + (size_t)d * I_ * O_ + o;
    float y = 0.f;
    for (int i = 0; i < I_; ++i) y += xp[i] * wp[(size_t)i * O_];
    acc += var[(size_t)n * D_ + d] * (y + b1[(size_t)d * O_ + o]);
  }
  out[(size_t)n * O_ + o] = acc;
}

extern "C" void kernel_launch(void* const* d_in, const int* in_sizes, int n_in,
                              void* d_out, int out_size, void* d_ws, size_t ws_size,
                              hipStream_t stream) {
  const float* x   = (const float*)d_in[0];
  const float* var = (const float*)d_in[1];
  const float* W   = (const float*)d_in[2];
  const float* b1  = (const float*)d_in[3];
  float* out = (float*)d_out;

  const size_t wt_bytes = (size_t)D_ * I_ * O_ * 2;  // 32 MB
  const size_t xb_bytes = (size_t)N_ * I_ * 2;       // 4 MB
  if (ws_size >= wt_bytes + xb_bytes) {
    unsigned short* wt = (unsigned short*)d_ws;
    unsigned short* xb = (unsigned short*)((char*)d_ws + wt_bytes);
    k_cvt_x<<<dim3((N_ * I_) / (256 * 8)), dim3(256), 0, stream>>>(x, xb);
    k_cvt_w<<<dim3(D_ * 64), dim3(256), 0, stream>>>(W, wt);
    k_bias<<<dim3(N_ / 16), dim3(256), 0, stream>>>(var, b1, out);
    k_gemm<<<dim3((N_ / BM) * (O_ / BN) * SPLITS), dim3(512), 0, stream>>>(xb, wt, var, out);
  } else {
    k_naive<<<dim3(N_, O_ / 128), dim3(128), 0, stream>>>(x, var, W, b1, out);
  }
}

// Round 12
// 230.482 us; speedup vs baseline: 1.1198x; 1.1198x over previous
//
#include <hip/hip_runtime.h>
#include <hip/hip_bf16.h>
#include <stdint.h>
#include <stddef.h>

#define N_ 4096
#define D_ 64
#define I_ 512
#define O_ 512

#define BM 256
#define BN 128
#define SPLITS 4
#define DPG 16                 /* d-values per block */
#define PAIRS (DPG / 2)        /* 8 */
#define KXS 16                 /* K=512 / BK=32 chunks per pair */
#define NS (PAIRS * KXS)       /* 128 supersteps */
#define SLOTA (128 * 128)      /* A slot: 256r x 32k bf16 packed [128][128B] */
#define SLOTB (64 * 128)       /* B slot per d: 128r x 32k packed [64][128B] */

typedef float  floatx4 __attribute__((ext_vector_type(4)));
typedef short  shortx8 __attribute__((ext_vector_type(8)));
typedef __bf16 bf16x8  __attribute__((ext_vector_type(8)));

__device__ __forceinline__ void gload_lds16(const void* g, void* l) {
  __builtin_amdgcn_global_load_lds(
      (const __attribute__((address_space(1))) void*)g,
      (__attribute__((address_space(3))) void*)l, 16, 0, 0);
}

__device__ __forceinline__ unsigned short f2bf(float f) {
  union { float f; unsigned int u; } c; c.f = f;
  unsigned int u = c.u;
  return (unsigned short)((u + 0x7fffu + ((u >> 16) & 1u)) >> 16);  // RNE
}

__device__ __forceinline__ void mfma_bf16(floatx4& c, shortx8 a, shortx8 b) {
  union { shortx8 s; bf16x8 h; } ua, ub;
  ua.s = a; ub.s = b;
  c = __builtin_amdgcn_mfma_f32_16x16x32_bf16(ua.h, ub.h, c, 0, 0, 0);
}

// ---------- fused pre-pass: cvt_x | cvt_w(transpose) | bias, one launch ----------
// blocks [0,1024): x f32->bf16 ; [1024,5120): W[d][i][o]->Wt[d][o][i] bf16 ;
// [5120,5376): out = sum_d var*b1 (bias-init for gemm atomics).
__global__ __launch_bounds__(256) void k_pre(
    const float* __restrict__ x, const float* __restrict__ W,
    const float* __restrict__ var, const float* __restrict__ b1,
    unsigned short* __restrict__ xb, unsigned short* __restrict__ wt,
    float* __restrict__ out) {
  __shared__ unsigned short T[64][72];
  __shared__ float vs[16][64];
  const int b = blockIdx.x;
  const int t = threadIdx.x;

  if (b < 1024) {                       // ---- cvt_x ----
    int idx = (b * 256 + t) * 8;
    floatx4 a = *(const floatx4*)(x + idx);
    floatx4 c = *(const floatx4*)(x + idx + 4);
    shortx8 o;
    o[0] = (short)f2bf(a[0]); o[1] = (short)f2bf(a[1]);
    o[2] = (short)f2bf(a[2]); o[3] = (short)f2bf(a[3]);
    o[4] = (short)f2bf(c[0]); o[5] = (short)f2bf(c[1]);
    o[6] = (short)f2bf(c[2]); o[7] = (short)f2bf(c[3]);
    *(shortx8*)(xb + idx) = o;
  } else if (b < 5120) {                // ---- cvt_w (64x64 LDS transpose) ----
    int bid = b - 1024;
    int d  = bid >> 6;
    int it = (bid >> 3) & 7;
    int ot = bid & 7;
    int i0 = it * 64, o0 = ot * 64;
    const float* wp = W + ((size_t)d * I_ + i0) * O_ + o0;
    #pragma unroll
    for (int j = 0; j < 16; ++j) {
      int idx = j * 256 + t;
      int r = idx >> 6, c = idx & 63;
      T[r][c] = f2bf(wp[(size_t)r * O_ + c]);
    }
    __syncthreads();
    unsigned short* op = wt + ((size_t)d * O_ + o0) * I_ + i0;
    #pragma unroll
    for (int j = 0; j < 16; ++j) {
      int idx = j * 256 + t;
      int r = idx >> 6, c = idx & 63;
      op[(size_t)r * I_ + c] = T[c][r];
    }
  } else {                              // ---- bias ----
    int n0 = (b - 5120) * 16;
    #pragma unroll
    for (int j = 0; j < 4; ++j) {
      int idx = j * 256 + t;
      vs[idx >> 6][idx & 63] = var[(size_t)n0 * D_ + idx];
    }
    __syncthreads();
    float a0[16], a1[16];
    #pragma unroll
    for (int r = 0; r < 16; ++r) { a0[r] = 0.f; a1[r] = 0.f; }
    for (int d = 0; d < D_; ++d) {
      float b0 = b1[(size_t)d * O_ + t];
      float bb = b1[(size_t)d * O_ + 256 + t];
      #pragma unroll
      for (int r = 0; r < 16; ++r) { a0[r] += vs[r][d] * b0; a1[r] += vs[r][d] * bb; }
    }
    #pragma unroll
    for (int r = 0; r < 16; ++r) {
      out[(size_t)(n0 + r) * O_ + t]       = a0[r];
      out[(size_t)(n0 + r) * O_ + 256 + t] = a1[r];
    }
  }
}

// ---------- main: ring-4 counted-vmcnt (R8 skeleton), compiler-scheduled reads ----------
// Changes vs R8 (146.6us, MfmaUtil 41%, VALUBusy 20%): (1) no explicit lgkm
// waits / sched_barriers / setprio in the body — frag reads are plain C++
// loads, the compiler inserts exact per-use lgkmcnt and may interleave reads
// with MFMA0; (2) inner loop unroll 4 — ring slot (s&3), fold guard (s&15),
// stage slots become compile-time. Sync skeleton UNCHANGED: per-superstep
// {stage(s+2); compute; own-vmcnt(4) publication; s_barrier}.
__global__ __launch_bounds__(512) void k_gemm(
    const unsigned short* __restrict__ xb, const unsigned short* __restrict__ wt,
    const float* __restrict__ var, float* __restrict__ out) {
  __shared__ alignas(16) char lA[4][SLOTA];       // 64 KB
  __shared__ alignas(16) char lB[4][2][SLOTB];    // 64 KB
  __shared__ alignas(16) float lV[DPG * BM];      // 16 KB

  const int tid = threadIdx.x;
  const int bid = blockIdx.x;
  const int g  = bid & 15;          // (ot, split) — XCD-local W-slice sharing
  const int mt = bid >> 4;
  const int ot = g >> 2, split = g & 3;
  const int brow = mt * BM, bcol = ot * BN, d0 = split * DPG;

  const int lane = tid & 63, wid = tid >> 6;
  const int wr = wid >> 1, wc = wid & 1;        // 4M x 2N waves, 64x64 each
  const int l15 = lane & 15, l4 = lane >> 4;

  #pragma unroll
  for (int j = 0; j < (DPG * BM) / 512; ++j) {
    int idx = j * 512 + tid;
    int dd = idx >> 8, row = idx & (BM - 1);
    lV[idx] = var[(size_t)(brow + row) * D_ + d0 + dd];
  }

  const char* xbB = (const char*)xb;
  const char* wtB = (const char*)wt;

  int pbA[2]; size_t gbA[2];
  #pragma unroll
  for (int c = 0; c < 2; ++c) {
    int pb = (c * 512 + tid) << 4;
    int rl = pb >> 7;
    int colG = (pb & 127) ^ ((rl & 7) << 4);
    int r_src = rl + ((colG >> 6) << 7);
    int k_src = (colG & 63) >> 1;
    pbA[c] = pb;
    gbA[c] = ((size_t)(brow + r_src) * I_ + k_src) * 2;
  }
  int pbB; size_t gbB;
  {
    int pb = tid << 4;
    int rl = pb >> 7;
    int colG = (pb & 127) ^ ((rl & 7) << 4);
    int r_src = rl + ((colG >> 6) << 6);
    int k_src = (colG & 63) >> 1;
    pbB = pb;
    gbB = ((size_t)(bcol + r_src) * I_ + k_src) * 2;
  }

  int avOff[4], bvOff[4];
  #pragma unroll
  for (int m = 0; m < 4; ++m) {
    int r = wr * 64 + m * 16 + l15;
    int rl = r & 127;
    avOff[m] = rl * 128 + ((((r >> 7) << 6) + l4 * 16) ^ ((rl & 7) << 4));
  }
  #pragma unroll
  for (int n = 0; n < 4; ++n) {
    int r = wc * 64 + n * 16 + l15;
    int rl = r & 63;
    bvOff[n] = rl * 128 + (((wc << 6) + l4 * 16) ^ ((rl & 7) << 4));
  }

  auto stage_A = [&](int s) {
    const int kx = s & 15;
    char* la = (char*)&lA[s & 3][0];
    #pragma unroll
    for (int c = 0; c < 2; ++c)
      gload_lds16(xbB + gbA[c] + (size_t)kx * 64, la + pbA[c]);
  };
  auto stage_B = [&](int s) {
    const int d = d0 + 2 * (s >> 4);
    const int kx = s & 15;
    const char* src = wtB + (size_t)d * (I_ * O_ * 2) + gbB + (size_t)kx * 64;
    gload_lds16(src, (char*)&lB[s & 3][0][0] + pbB);
    gload_lds16(src + (size_t)(I_ * O_ * 2), (char*)&lB[s & 3][1][0] + pbB);
  };

  // prologue: stage supersteps 0,1; certify 0 (vmcnt(4) leaves s1 flying)
  stage_A(0); stage_B(0); stage_A(1); stage_B(1);

  const floatx4 vzero = {0.f, 0.f, 0.f, 0.f};
  floatx4 master[4][4];
  #pragma unroll
  for (int m = 0; m < 4; ++m)
    #pragma unroll
    for (int n = 0; n < 4; ++n) master[m][n] = vzero;

  asm volatile("s_waitcnt vmcnt(4) lgkmcnt(0)" ::: "memory");
  __builtin_amdgcn_sched_barrier(0);
  __builtin_amdgcn_s_barrier();

  #pragma unroll 1
  for (int p = 0; p < PAIRS; ++p) {
    floatx4 acc0[4][4], acc1[4][4];
    #pragma unroll
    for (int m = 0; m < 4; ++m)
      #pragma unroll
      for (int n = 0; n < 4; ++n) { acc0[m][n] = vzero; acc1[m][n] = vzero; }

    #pragma unroll 4
    for (int kx = 0; kx < KXS; ++kx) {
      const int s = p * KXS + kx;
      const char* aS  = (const char*)&lA[s & 3][0];
      const char* bS0 = (const char*)&lB[s & 3][0][0];
      const char* bS1 = (const char*)&lB[s & 3][1][0];
      shortx8 av[4], bv0[4], bv1[4];

      // frag reads (plain loads — compiler inserts exact lgkm waits)
      #pragma unroll
      for (int m = 0; m < 4; ++m) av[m] = *(const shortx8*)(aS + avOff[m]);
      #pragma unroll
      for (int n = 0; n < 4; ++n) bv0[n] = *(const shortx8*)(bS0 + bvOff[n]);
      #pragma unroll
      for (int n = 0; n < 4; ++n) bv1[n] = *(const shortx8*)(bS1 + bvOff[n]);
      // staging for s+2 (vmcnt queue)
      if (s + 2 < NS) { stage_A(s + 2); stage_B(s + 2); }

      #pragma unroll
      for (int m = 0; m < 4; ++m)
        #pragma unroll
        for (int n = 0; n < 4; ++n) mfma_bf16(acc0[m][n], av[m], bv0[n]);
      #pragma unroll
      for (int m = 0; m < 4; ++m)
        #pragma unroll
        for (int n = 0; n < 4; ++n) mfma_bf16(acc1[m][n], av[m], bv1[n]);

      if ((s & 15) == 15) {              // pair end (compile-time under unroll)
        int pp = s >> 4;
        #pragma unroll
        for (int m = 0; m < 4; ++m) {
          int rbase = wr * 64 + m * 16 + l4 * 4;
          floatx4 v0 = *(const floatx4*)&lV[(2 * pp) * BM + rbase];
          floatx4 v1 = *(const floatx4*)&lV[(2 * pp + 1) * BM + rbase];
          #pragma unroll
          for (int n = 0; n < 4; ++n)
            #pragma unroll
            for (int r = 0; r < 4; ++r) {
              master[m][n][r] += v0[r] * acc0[m][n][r] + v1[r] * acc1[m][n][r];
              acc0[m][n][r] = 0.f;
              acc1[m][n][r] = 0.f;
            }
        }
      }

      // publication: certify own s+1 loads (leave s+2's 4 in flight), barrier
      if (s + 2 < NS)      { asm volatile("s_waitcnt vmcnt(4)" ::: "memory"); }
      else if (s + 1 < NS) { asm volatile("s_waitcnt vmcnt(0)" ::: "memory"); }
      __builtin_amdgcn_sched_barrier(0);
      __builtin_amdgcn_s_barrier();
      __builtin_amdgcn_sched_barrier(0);
    }
  }

  // epilogue: atomic add onto bias-initialized out
  #pragma unroll
  for (int m = 0; m < 4; ++m) {
    int row0 = brow + wr * 64 + m * 16 + l4 * 4;
    #pragma unroll
    for (int n = 0; n < 4; ++n) {
      int col = bcol + wc * 64 + n * 16 + l15;
      #pragma unroll
      for (int r = 0; r < 4; ++r)
        atomicAdd(out + (size_t)(row0 + r) * O_ + col, master[m][n][r]);
    }
  }
}

// ---------- fallback (only if ws too small for bf16 staging) ----------
__global__ void k_naive(const float* __restrict__ x, const float* __restrict__ var,
                        const float* __restrict__ w, const float* __restrict__ b1,
                        float* __restrict__ out) {
  int n = blockIdx.x;
  int o = blockIdx.y * 128 + threadIdx.x;
  const float* xp = x + (size_t)n * I_;
  float acc = 0.f;
  for (int d = 0; d < D_; ++d) {
    const float* wp = w + (size_t)d * I_ * O_ + o;
    float y = 0.f;
    for (int i = 0; i < I_; ++i) y += xp[i] * wp[(size_t)i * O_];
    acc += var[(size_t)n * D_ + d] * (y + b1[(size_t)d * O_ + o]);
  }
  out[(size_t)n * O_ + o] = acc;
}

extern "C" void kernel_launch(void* const* d_in, const int* in_sizes, int n_in,
                              void* d_out, int out_size, void* d_ws, size_t ws_size,
                              hipStream_t stream) {
  const float* x   = (const float*)d_in[0];
  const float* var = (const float*)d_in[1];
  const float* W   = (const float*)d_in[2];
  const float* b1  = (const float*)d_in[3];
  float* out = (float*)d_out;

  const size_t wt_bytes = (size_t)D_ * I_ * O_ * 2;  // 32 MB
  const size_t xb_bytes = (size_t)N_ * I_ * 2;       // 4 MB
  if (ws_size >= wt_bytes + xb_bytes) {
    unsigned short* wt = (unsigned short*)d_ws;
    unsigned short* xb = (unsigned short*)((char*)d_ws + wt_bytes);
    k_pre<<<dim3(5376), dim3(256), 0, stream>>>(x, W, var, b1, xb, wt, out);
    k_gemm<<<dim3((N_ / BM) * (O_ / BN) * SPLITS), dim3(512), 0, stream>>>(xb, wt, var, out);
  } else {
    k_naive<<<dim3(N_, O_ / 128), dim3(128), 0, stream>>>(x, var, W, b1, out);
  }
}

// Round 13
// 169.842 us; speedup vs baseline: 1.5197x; 1.3570x over previous
//
#include <hip/hip_runtime.h>
#include <hip/hip_bf16.h>
#include <stdint.h>
#include <stddef.h>

#define N_ 4096
#define D_ 64
#define I_ 512
#define O_ 512

#define BM 256
#define BN 128
#define SPLITS 4
#define DPG 16                 /* d-values per block */
#define PAIRS (DPG / 2)        /* 8 */
#define KXS 16                 /* K=512 / BK=32 chunks per pair */
#define NS (PAIRS * KXS)       /* 128 supersteps */
#define SLOTA (128 * 128)      /* A slot: 256r x 32k bf16 packed [128][128B] */
#define SLOTB (64 * 128)       /* B slot per d: 128r x 32k packed [64][128B] */

typedef float  floatx4 __attribute__((ext_vector_type(4)));
typedef short  shortx8 __attribute__((ext_vector_type(8)));
typedef __bf16 bf16x8  __attribute__((ext_vector_type(8)));

__device__ __forceinline__ void gload_lds16(const void* g, void* l) {
  __builtin_amdgcn_global_load_lds(
      (const __attribute__((address_space(1))) void*)g,
      (__attribute__((address_space(3))) void*)l, 16, 0, 0);
}

__device__ __forceinline__ unsigned short f2bf(float f) {
  union { float f; unsigned int u; } c; c.f = f;
  unsigned int u = c.u;
  return (unsigned short)((u + 0x7fffu + ((u >> 16) & 1u)) >> 16);  // RNE
}

__device__ __forceinline__ void mfma_bf16(floatx4& c, shortx8 a, shortx8 b) {
  union { shortx8 s; bf16x8 h; } ua, ub;
  ua.s = a; ub.s = b;
  c = __builtin_amdgcn_mfma_f32_16x16x32_bf16(ua.h, ub.h, c, 0, 0, 0);
}

// ---------- fused pre-pass: cvt_x | cvt_w(transpose) | bias, one launch ----------
// blocks [0,1024): x f32->bf16 ; [1024,5120): W[d][i][o]->Wt[d][o][i] bf16 ;
// [5120,5376): out = sum_d var*b1 (bias-init for gemm atomics).
// Verified in R12 (~10us, correct).
__global__ __launch_bounds__(256) void k_pre(
    const float* __restrict__ x, const float* __restrict__ W,
    const float* __restrict__ var, const float* __restrict__ b1,
    unsigned short* __restrict__ xb, unsigned short* __restrict__ wt,
    float* __restrict__ out) {
  __shared__ unsigned short T[64][72];
  __shared__ float vs[16][64];
  const int b = blockIdx.x;
  const int t = threadIdx.x;

  if (b < 1024) {                       // ---- cvt_x ----
    int idx = (b * 256 + t) * 8;
    floatx4 a = *(const floatx4*)(x + idx);
    floatx4 c = *(const floatx4*)(x + idx + 4);
    shortx8 o;
    o[0] = (short)f2bf(a[0]); o[1] = (short)f2bf(a[1]);
    o[2] = (short)f2bf(a[2]); o[3] = (short)f2bf(a[3]);
    o[4] = (short)f2bf(c[0]); o[5] = (short)f2bf(c[1]);
    o[6] = (short)f2bf(c[2]); o[7] = (short)f2bf(c[3]);
    *(shortx8*)(xb + idx) = o;
  } else if (b < 5120) {                // ---- cvt_w (64x64 LDS transpose) ----
    int bid = b - 1024;
    int d  = bid >> 6;
    int it = (bid >> 3) & 7;
    int ot = bid & 7;
    int i0 = it * 64, o0 = ot * 64;
    const float* wp = W + ((size_t)d * I_ + i0) * O_ + o0;
    #pragma unroll
    for (int j = 0; j < 16; ++j) {
      int idx = j * 256 + t;
      int r = idx >> 6, c = idx & 63;
      T[r][c] = f2bf(wp[(size_t)r * O_ + c]);
    }
    __syncthreads();
    unsigned short* op = wt + ((size_t)d * O_ + o0) * I_ + i0;
    #pragma unroll
    for (int j = 0; j < 16; ++j) {
      int idx = j * 256 + t;
      int r = idx >> 6, c = idx & 63;
      op[(size_t)r * I_ + c] = T[c][r];
    }
  } else {                              // ---- bias ----
    int n0 = (b - 5120) * 16;
    #pragma unroll
    for (int j = 0; j < 4; ++j) {
      int idx = j * 256 + t;
      vs[idx >> 6][idx & 63] = var[(size_t)n0 * D_ + idx];
    }
    __syncthreads();
    float a0[16], a1[16];
    #pragma unroll
    for (int r = 0; r < 16; ++r) { a0[r] = 0.f; a1[r] = 0.f; }
    for (int d = 0; d < D_; ++d) {
      float b0 = b1[(size_t)d * O_ + t];
      float bb = b1[(size_t)d * O_ + 256 + t];
      #pragma unroll
      for (int r = 0; r < 16; ++r) { a0[r] += vs[r][d] * b0; a1[r] += vs[r][d] * bb; }
    }
    #pragma unroll
    for (int r = 0; r < 16; ++r) {
      out[(size_t)(n0 + r) * O_ + t]       = a0[r];
      out[(size_t)(n0 + r) * O_ + 256 + t] = a1[r];
    }
  }
}

// ---------- main: R8 kernel VERBATIM (146.6us, MfmaUtil 41%, 0 spills) ----------
// ring-4, one barrier/superstep, explicit lgkm waits keep live ranges tight
// (R12 showed removing them + unroll-4 -> scratch spills, 187MB writes).
__global__ __launch_bounds__(512) void k_gemm(
    const unsigned short* __restrict__ xb, const unsigned short* __restrict__ wt,
    const float* __restrict__ var, float* __restrict__ out) {
  __shared__ alignas(16) char lA[4][SLOTA];       // 64 KB
  __shared__ alignas(16) char lB[4][2][SLOTB];    // 64 KB
  __shared__ alignas(16) float lV[DPG * BM];      // 16 KB

  const int tid = threadIdx.x;
  const int bid = blockIdx.x;
  const int g  = bid & 15;          // (ot, split) — XCD-local W-slice sharing
  const int mt = bid >> 4;
  const int ot = g >> 2, split = g & 3;
  const int brow = mt * BM, bcol = ot * BN, d0 = split * DPG;

  const int lane = tid & 63, wid = tid >> 6;
  const int wr = wid >> 1, wc = wid & 1;        // 4M x 2N waves, 64x64 each
  const int l15 = lane & 15, l4 = lane >> 4;

  #pragma unroll
  for (int j = 0; j < (DPG * BM) / 512; ++j) {
    int idx = j * 512 + tid;
    int dd = idx >> 8, row = idx & (BM - 1);
    lV[idx] = var[(size_t)(brow + row) * D_ + d0 + dd];
  }

  const char* xbB = (const char*)xb;
  const char* wtB = (const char*)wt;

  int pbA[2]; size_t gbA[2];
  #pragma unroll
  for (int c = 0; c < 2; ++c) {
    int pb = (c * 512 + tid) << 4;
    int rl = pb >> 7;
    int colG = (pb & 127) ^ ((rl & 7) << 4);
    int r_src = rl + ((colG >> 6) << 7);
    int k_src = (colG & 63) >> 1;
    pbA[c] = pb;
    gbA[c] = ((size_t)(brow + r_src) * I_ + k_src) * 2;
  }
  int pbB; size_t gbB;
  {
    int pb = tid << 4;
    int rl = pb >> 7;
    int colG = (pb & 127) ^ ((rl & 7) << 4);
    int r_src = rl + ((colG >> 6) << 6);
    int k_src = (colG & 63) >> 1;
    pbB = pb;
    gbB = ((size_t)(bcol + r_src) * I_ + k_src) * 2;
  }

  int avOff[4], bvOff[4];
  #pragma unroll
  for (int m = 0; m < 4; ++m) {
    int r = wr * 64 + m * 16 + l15;
    int rl = r & 127;
    avOff[m] = rl * 128 + ((((r >> 7) << 6) + l4 * 16) ^ ((rl & 7) << 4));
  }
  #pragma unroll
  for (int n = 0; n < 4; ++n) {
    int r = wc * 64 + n * 16 + l15;
    int rl = r & 63;
    bvOff[n] = rl * 128 + (((wc << 6) + l4 * 16) ^ ((rl & 7) << 4));
  }

  auto stage_A = [&](int s) {
    const int kx = s & 15;
    char* la = (char*)&lA[s & 3][0];
    #pragma unroll
    for (int c = 0; c < 2; ++c)
      gload_lds16(xbB + gbA[c] + (size_t)kx * 64, la + pbA[c]);
  };
  auto stage_B = [&](int s) {
    const int d = d0 + 2 * (s >> 4);
    const int kx = s & 15;
    const char* src = wtB + (size_t)d * (I_ * O_ * 2) + gbB + (size_t)kx * 64;
    gload_lds16(src, (char*)&lB[s & 3][0][0] + pbB);
    gload_lds16(src + (size_t)(I_ * O_ * 2), (char*)&lB[s & 3][1][0] + pbB);
  };

  // prologue: stage supersteps 0 and 1; publish 0 (vmcnt(4) leaves s1 flying)
  stage_A(0); stage_B(0); stage_A(1); stage_B(1);

  const floatx4 vzero = {0.f, 0.f, 0.f, 0.f};
  floatx4 master[4][4];
  #pragma unroll
  for (int m = 0; m < 4; ++m)
    #pragma unroll
    for (int n = 0; n < 4; ++n) master[m][n] = vzero;

  asm volatile("s_waitcnt vmcnt(4) lgkmcnt(0)" ::: "memory");
  __builtin_amdgcn_sched_barrier(0);
  __builtin_amdgcn_s_barrier();

  for (int p = 0; p < PAIRS; ++p) {
    floatx4 acc0[4][4], acc1[4][4];
    #pragma unroll
    for (int m = 0; m < 4; ++m)
      #pragma unroll
      for (int n = 0; n < 4; ++n) { acc0[m][n] = vzero; acc1[m][n] = vzero; }

    #pragma unroll 1
    for (int kx = 0; kx < KXS; ++kx) {
      const int s = p * KXS + kx;
      const char* aS  = (const char*)&lA[s & 3][0];
      const char* bS0 = (const char*)&lB[s & 3][0][0];
      const char* bS1 = (const char*)&lB[s & 3][1][0];
      shortx8 av[4], bv0[4], bv1[4];

      // issue all 12 ds_reads (in-order lgkm queue: av, bv0, bv1)
      #pragma unroll
      for (int m = 0; m < 4; ++m) av[m] = *(const shortx8*)(aS + avOff[m]);
      #pragma unroll
      for (int n = 0; n < 4; ++n) bv0[n] = *(const shortx8*)(bS0 + bvOff[n]);
      #pragma unroll
      for (int n = 0; n < 4; ++n) bv1[n] = *(const shortx8*)(bS1 + bvOff[n]);
      // issue next-next staging (4 gloads, vmcnt queue)
      if (s + 2 < NS) { stage_A(s + 2); stage_B(s + 2); }

      // own av+bv0 done (first 8 of 12 in-order ds queue)
      asm volatile("s_waitcnt lgkmcnt(4)" ::: "memory");
      __builtin_amdgcn_sched_barrier(0);
      __builtin_amdgcn_s_setprio(1);
      #pragma unroll
      for (int m = 0; m < 4; ++m)
        #pragma unroll
        for (int n = 0; n < 4; ++n) mfma_bf16(acc0[m][n], av[m], bv0[n]);
      __builtin_amdgcn_sched_barrier(0);
      asm volatile("s_waitcnt lgkmcnt(0)" ::: "memory");
      __builtin_amdgcn_sched_barrier(0);
      #pragma unroll
      for (int m = 0; m < 4; ++m)
        #pragma unroll
        for (int n = 0; n < 4; ++n) mfma_bf16(acc1[m][n], av[m], bv1[n]);
      __builtin_amdgcn_s_setprio(0);

      // publication: certify own s+1 loads (leave s+2's 4 in flight), barrier
      if (s + 2 < NS)      { asm volatile("s_waitcnt vmcnt(4)" ::: "memory"); }
      else if (s + 1 < NS) { asm volatile("s_waitcnt vmcnt(0)" ::: "memory"); }
      __builtin_amdgcn_s_barrier();
    }

    // master += var[row,da]*acc0 + var[row,da+1]*acc1
    #pragma unroll
    for (int m = 0; m < 4; ++m) {
      int rbase = wr * 64 + m * 16 + l4 * 4;
      floatx4 v0 = *(const floatx4*)&lV[(2 * p) * BM + rbase];
      floatx4 v1 = *(const floatx4*)&lV[(2 * p + 1) * BM + rbase];
      #pragma unroll
      for (int n = 0; n < 4; ++n)
        #pragma unroll
        for (int r = 0; r < 4; ++r)
          master[m][n][r] += v0[r] * acc0[m][n][r] + v1[r] * acc1[m][n][r];
    }
  }

  // epilogue: atomic add onto bias-initialized out
  #pragma unroll
  for (int m = 0; m < 4; ++m) {
    int row0 = brow + wr * 64 + m * 16 + l4 * 4;
    #pragma unroll
    for (int n = 0; n < 4; ++n) {
      int col = bcol + wc * 64 + n * 16 + l15;
      #pragma unroll
      for (int r = 0; r < 4; ++r)
        atomicAdd(out + (size_t)(row0 + r) * O_ + col, master[m][n][r]);
    }
  }
}

// ---------- fallback (only if ws too small for bf16 staging) ----------
__global__ void k_naive(const float* __restrict__ x, const float* __restrict__ var,
                        const float* __restrict__ w, const float* __restrict__ b1,
                        float* __restrict__ out) {
  int n = blockIdx.x;
  int o = blockIdx.y * 128 + threadIdx.x;
  const float* xp = x + (size_t)n * I_;
  float acc = 0.f;
  for (int d = 0; d < D_; ++d) {
    const float* wp = w + (size_t)d * I_ * O_ + o;
    float y = 0.f;
    for (int i = 0; i < I_; ++i) y += xp[i] * wp[(size_t)i * O_];
    acc += var[(size_t)n * D_ + d] * (y + b1[(size_t)d * O_ + o]);
  }
  out[(size_t)n * O_ + o] = acc;
}

extern "C" void kernel_launch(void* const* d_in, const int* in_sizes, int n_in,
                              void* d_out, int out_size, void* d_ws, size_t ws_size,
                              hipStream_t stream) {
  const float* x   = (const float*)d_in[0];
  const float* var = (const float*)d_in[1];
  const float* W   = (const float*)d_in[2];
  const float* b1  = (const float*)d_in[3];
  float* out = (float*)d_out;

  const size_t wt_bytes = (size_t)D_ * I_ * O_ * 2;  // 32 MB
  const size_t xb_bytes = (size_t)N_ * I_ * 2;       // 4 MB
  if (ws_size >= wt_bytes + xb_bytes) {
    unsigned short* wt = (unsigned short*)d_ws;
    unsigned short* xb = (unsigned short*)((char*)d_ws + wt_bytes);
    k_pre<<<dim3(5376), dim3(256), 0, stream>>>(x, W, var, b1, xb, wt, out);
    k_gemm<<<dim3((N_ / BM) * (O_ / BN) * SPLITS), dim3(512), 0, stream>>>(xb, wt, var, out);
  } else {
    k_naive<<<dim3(N_, O_ / 128), dim3(128), 0, stream>>>(x, var, W, b1, out);
  }
}